// Round 8
// baseline (73.945 us; speedup 1.0000x reference)
//
#include <hip/hip_runtime.h>
#include <math.h>

#define KK 8
#define LOG2E   1.4426950408889634f
#define HL2E    0.7213475204444817f   // 0.5 * log2(e)
#define LN2     0.6931471805599453f
#define LOG2PI  1.8378770664093453f
#define C2CONST 5.3029936094f         // 2 * LOG2PI * LOG2E
#define L2CLIP8 -26.575424759f        // log2(1e-8)

// ---------------------------------------------------------------------------
// Kernel 1: grid = M*4 blocks x 256 threads. Block b: m=b>>2, points
// [(b&3)*1024,+1024); wave w owns 256 of them (4/lane). NO __syncthreads:
// each wave's lanes 0-7 redundantly compute component params into a per-wave
// LDS slab (wave-synchronous ds_write->ds_read). Setup uses bare v_exp/v_log
// builtins, c2 fully in log2 domain. Each wave butterfly-reduces its resp
// partials and lanes 0-7 store them to ws[(m*16+sub*4+w)*8+k] — no atomics,
// no memset (every ws slot written before gmm_norm reads it).
// NOTE: per-point softmax MUST keep max-subtraction (R3 bug: collective exp2
// underflow zeroes responsibility mass).
// NOTE: no 2nd __launch_bounds__ arg (R4: treated as min-blocks/CU -> VGPR=64
// -> 458 MB/dispatch scratch spill).
// ---------------------------------------------------------------------------
__global__ __launch_bounds__(256) void gmm_main(const float* __restrict__ phi,
                                                const float* __restrict__ X,
                                                float* __restrict__ ws) {
    __shared__ float4 sp[4][KK][4];   // per-wave param slabs

    const int b = blockIdx.x;
    const int m = b >> 2;
    const int sub = b & 3;
    const int t = threadIdx.x;
    const int w = t >> 6;
    const int lane = t & 63;
    const float* row = phi + m * 120;

    // issue X loads first so they overlap the setup chain
    const float4* X4 = reinterpret_cast<const float4*>(X);
    float4 xv[4];
    #pragma unroll
    for (int i = 0; i < 4; ++i) xv[i] = X4[sub * 1024 + w * 256 + i * 64 + lane];

    if (lane < KK) {
        // log2(pi_k) via log2-domain softmax (bare v_exp/v_log only)
        float mx = row[0];
        #pragma unroll
        for (int j = 1; j < KK; ++j) mx = fmaxf(mx, row[j]);
        float s = 0.f;
        #pragma unroll
        for (int j = 0; j < KK; ++j)
            s += __builtin_amdgcn_exp2f((row[j] - mx) * LOG2E);
        float l2pi = fmaxf((row[lane] - mx) * LOG2E - __builtin_amdgcn_logf(s),
                           L2CLIP8);   // log2(clip(pi,1e-8))

        const float* muk = row + 8 + lane * 4;
        const float* Lv  = row + 40 + lane * 10;
        // tril(D=4) order: l00,l10,l11,l20,l21,l22,l30,l31,l32,l33
        float l00 = Lv[0], l10 = Lv[1], l11 = Lv[2], l20 = Lv[3], l21 = Lv[4],
              l22 = Lv[5], l30 = Lv[6], l31 = Lv[7], l32 = Lv[8], l33 = Lv[9];
        float i0 = 1.f / l00, i1 = 1.f / l11, i2 = 1.f / l22, i3 = 1.f / l33;
        // W = inv(L), lower triangular (== forward-substitution coefficients)
        float w00 = i0;
        float w10 = -i1 * l10 * w00;
        float w11 = i1;
        float w20 = -i2 * (l20 * w00 + l21 * w10);
        float w21 = -i2 * (l21 * w11);
        float w22 = i2;
        float w30 = -i3 * (l30 * w00 + l31 * w10 + l32 * w20);
        float w31 = -i3 * (l31 * w11 + l32 * w21);
        float w32 = -i3 * (l32 * w22);
        float w33 = i3;
        // sum of log2|l_ii| (clip 1e-8);  c2 = l2pi - 2*log2(2pi) - sum
        float sl = __builtin_amdgcn_logf(fmaxf(fabsf(l00), 1e-8f)) +
                   __builtin_amdgcn_logf(fmaxf(fabsf(l11), 1e-8f)) +
                   __builtin_amdgcn_logf(fmaxf(fabsf(l22), 1e-8f)) +
                   __builtin_amdgcn_logf(fmaxf(fabsf(l33), 1e-8f));
        float c2 = l2pi - C2CONST - sl;
        sp[w][lane][0] = make_float4(muk[0], muk[1], muk[2], muk[3]);
        sp[w][lane][1] = make_float4(w00, w10, w11, w20);
        sp[w][lane][2] = make_float4(w21, w22, w30, w31);
        sp[w][lane][3] = make_float4(w32, w33, c2, 0.f);
    }
    // no barrier: ds_write -> ds_read dependency is wave-synchronous

    float acc[KK];
    #pragma unroll
    for (int k = 0; k < KK; ++k) acc[k] = 0.f;

    float lj[4][KK];
    #pragma unroll
    for (int k = 0; k < KK; ++k) {
        float4 p0 = sp[w][k][0], p1 = sp[w][k][1],
               p2 = sp[w][k][2], p3 = sp[w][k][3];
        // mu=p0; w00,w10,w11,w20=p1; w21,w22,w30,w31=p2; w32,w33,c2=p3
        #pragma unroll
        for (int i = 0; i < 4; ++i) {
            float d0 = xv[i].x - p0.x;
            float d1 = xv[i].y - p0.y;
            float d2 = xv[i].z - p0.z;
            float d3 = xv[i].w - p0.w;
            float a0 = d0 * p1.x;
            float a1 = fmaf(p1.y, d0, d1 * p1.z);
            float a2 = fmaf(p1.w, d0, fmaf(p2.x, d1, d2 * p2.y));
            float a3 = fmaf(p2.z, d0, fmaf(p2.w, d1, fmaf(p3.x, d2, d3 * p3.y)));
            float sq = fmaf(a0, a0, fmaf(a1, a1, fmaf(a2, a2, a3 * a3)));
            lj[i][k] = fmaf(-HL2E, sq, p3.z);             // log2-domain
        }
    }
    #pragma unroll
    for (int i = 0; i < 4; ++i) {
        float mx = lj[i][0];
        #pragma unroll
        for (int k = 1; k < KK; ++k) mx = fmaxf(mx, lj[i][k]);
        float e[KK], s = 0.f;
        #pragma unroll
        for (int k = 0; k < KK; ++k) {
            e[k] = __builtin_amdgcn_exp2f(lj[i][k] - mx); // bare v_exp_f32
            s += e[k];
        }
        float inv = __builtin_amdgcn_rcpf(s);             // s >= 1 (max term = 1)
        #pragma unroll
        for (int k = 0; k < KK; ++k) acc[k] = fmaf(e[k], inv, acc[k]);
    }

    // per-wave butterfly reduce; lanes 0-7 store this wave's partials
    #pragma unroll
    for (int k = 0; k < KK; ++k) {
        float v = acc[k];
        #pragma unroll
        for (int off = 32; off; off >>= 1) v += __shfl_xor(v, off, 64);
        acc[k] = v;
    }
    if (lane < KK) {
        int p = m * 16 + sub * 4 + w;                     // wave-partial index
        ws[p * 8 + lane] = acc[lane];
    }
}

// ---------------------------------------------------------------------------
// Kernel 2: builds every z value itself, then column-normalizes (ddof=1) and
// writes d_out once. 80 blocks (one per column) x 512 threads (one per row).
// col<32: mu; 32-63: ln(clip|Ldiag|,1e-6); 64-71: softmax(pi); 72-79: resp =
// sum of 16 wave-partials (B-scaled; z-norm is scale-invariant — R5-verified).
// Branch is block-uniform -> no divergence.
// ---------------------------------------------------------------------------
__global__ __launch_bounds__(512) void gmm_norm(const float* __restrict__ phi,
                                                const float* __restrict__ ws,
                                                float* __restrict__ out, int M) {
    __shared__ float sw[8];
    const int col = blockIdx.x;
    const int t = threadIdx.x;    // row m
    const float* row = phi + t * 120;

    float v;
    if (col < 32) {
        v = row[8 + col];
    } else if (col < 64) {
        int j = col - 32, k = j >> 2, d = j & 3;
        int didx = (d == 0) ? 0 : (d == 1) ? 2 : (d == 2) ? 5 : 9;
        v = __builtin_amdgcn_logf(fmaxf(fabsf(row[40 + k * 10 + didx]), 1e-6f)) * LN2;
    } else if (col < 72) {
        int k = col - 64;
        float mx = row[0];
        #pragma unroll
        for (int j = 1; j < KK; ++j) mx = fmaxf(mx, row[j]);
        float s = 0.f;
        #pragma unroll
        for (int j = 0; j < KK; ++j)
            s += __builtin_amdgcn_exp2f((row[j] - mx) * LOG2E);
        v = __builtin_amdgcn_exp2f((row[k] - mx) * LOG2E) *
            __builtin_amdgcn_rcpf(s);
    } else {
        int k = col - 72;
        v = 0.f;
        #pragma unroll
        for (int q = 0; q < 16; ++q) v += ws[(t * 16 + q) * 8 + k];
    }

    float r = v;
    #pragma unroll
    for (int off = 32; off; off >>= 1) r += __shfl_xor(r, off, 64);
    if ((t & 63) == 0) sw[t >> 6] = r;
    __syncthreads();
    float tot = 0.f;
    #pragma unroll
    for (int w = 0; w < 8; ++w) tot += sw[w];
    float mean = tot / (float)M;
    __syncthreads();

    float d = v - mean;
    r = d * d;
    #pragma unroll
    for (int off = 32; off; off >>= 1) r += __shfl_xor(r, off, 64);
    if ((t & 63) == 0) sw[t >> 6] = r;
    __syncthreads();
    float tot2 = 0.f;
    #pragma unroll
    for (int w = 0; w < 8; ++w) tot2 += sw[w];
    float stdv = fmaxf(sqrtf(tot2 / (float)(M - 1)), 1e-6f);

    out[t * 80 + col] = d / stdv;
}

extern "C" void kernel_launch(void* const* d_in, const int* in_sizes, int n_in,
                              void* d_out, int out_size, void* d_ws, size_t ws_size,
                              hipStream_t stream) {
    const float* phi = (const float*)d_in[0];
    const float* X   = (const float*)d_in[1];
    const int M = in_sizes[0] / 120;  // 512
    float* ws = (float*)d_ws;         // M*16 wave-partials x 8 comps = 256 KB

    gmm_main<<<M * 4, 256, 0, stream>>>(phi, X, ws);
    gmm_norm<<<80, 512, 0, stream>>>(phi, ws, (float*)d_out, M);
}

// Round 9
// 72.634 us; speedup vs baseline: 1.0180x; 1.0180x over previous
//
#include <hip/hip_runtime.h>
#include <math.h>

#define KK 8
#define LOG2E   1.4426950408889634f
#define HL2E    0.7213475204444817f   // 0.5 * log2(e)
#define LN2     0.6931471805599453f
#define C2CONST 5.3029936094f         // 2 * log2(2*pi)
#define L2CLIP8 -26.575424759f        // log2(1e-8)

// ws layout: [0, 65536) floats: params (M*K blocks of 16 floats:
//   mu0..3, w00,w10,w11,w20, w21,w22,w30,w31, w32,w33,c2,pad)
// [65536, 131072): resp partials, transposed: part[(p*8+k)*M + m], p in [0,16)

// ---------------------------------------------------------------------------
// Kernel A: one thread per (m,k) component. Computes softmax(pi), W=L^{-1},
// log2-domain constant c2 -> param block in ws; also writes z prefix columns
// (mu, ln|Ldiag| clip 1e-6, pi) into d_out. v_exp/v_log builtins are base-2.
// ---------------------------------------------------------------------------
__global__ __launch_bounds__(256) void gmm_setup(const float* __restrict__ phi,
                                                 float* __restrict__ ws,
                                                 float* __restrict__ z) {
    const int tid = blockIdx.x * 256 + threadIdx.x;   // 0..4095
    const int m = tid >> 3, k = tid & 7;
    const float* row = phi + m * 120;

    float mx = row[0];
    #pragma unroll
    for (int j = 1; j < KK; ++j) mx = fmaxf(mx, row[j]);
    float s = 0.f;
    #pragma unroll
    for (int j = 0; j < KK; ++j)
        s += __builtin_amdgcn_exp2f((row[j] - mx) * LOG2E);
    float l2s = __builtin_amdgcn_logf(s);             // log2(s)
    float pik = __builtin_amdgcn_exp2f((row[k] - mx) * LOG2E) *
                __builtin_amdgcn_rcpf(s);
    float l2pi = fmaxf((row[k] - mx) * LOG2E - l2s, L2CLIP8);  // log2(clip pi)

    const float* muk = row + 8 + k * 4;
    const float* Lv  = row + 40 + k * 10;
    // tril(D=4) order: l00,l10,l11,l20,l21,l22,l30,l31,l32,l33
    float l00 = Lv[0], l10 = Lv[1], l11 = Lv[2], l20 = Lv[3], l21 = Lv[4],
          l22 = Lv[5], l30 = Lv[6], l31 = Lv[7], l32 = Lv[8], l33 = Lv[9];
    float i0 = 1.f / l00, i1 = 1.f / l11, i2 = 1.f / l22, i3 = 1.f / l33;
    // W = inv(L), lower triangular (== forward-substitution coefficients)
    float w00 = i0;
    float w10 = -i1 * l10 * w00;
    float w11 = i1;
    float w20 = -i2 * (l20 * w00 + l21 * w10);
    float w21 = -i2 * (l21 * w11);
    float w22 = i2;
    float w30 = -i3 * (l30 * w00 + l31 * w10 + l32 * w20);
    float w31 = -i3 * (l31 * w11 + l32 * w21);
    float w32 = -i3 * (l32 * w22);
    float w33 = i3;
    float sl = __builtin_amdgcn_logf(fmaxf(fabsf(l00), 1e-8f)) +
               __builtin_amdgcn_logf(fmaxf(fabsf(l11), 1e-8f)) +
               __builtin_amdgcn_logf(fmaxf(fabsf(l22), 1e-8f)) +
               __builtin_amdgcn_logf(fmaxf(fabsf(l33), 1e-8f));
    float c2 = l2pi - C2CONST - sl;                   // log2-domain constant

    float4* P = reinterpret_cast<float4*>(ws) + tid * 4;
    P[0] = make_float4(muk[0], muk[1], muk[2], muk[3]);
    P[1] = make_float4(w00, w10, w11, w20);
    P[2] = make_float4(w21, w22, w30, w31);
    P[3] = make_float4(w32, w33, c2, 0.f);

    // z prefix columns
    float* zr = z + m * 80;
    #pragma unroll
    for (int d = 0; d < 4; ++d) zr[k * 4 + d] = muk[d];
    zr[32 + k * 4 + 0] = __builtin_amdgcn_logf(fmaxf(fabsf(l00), 1e-6f)) * LN2;
    zr[32 + k * 4 + 1] = __builtin_amdgcn_logf(fmaxf(fabsf(l11), 1e-6f)) * LN2;
    zr[32 + k * 4 + 2] = __builtin_amdgcn_logf(fmaxf(fabsf(l22), 1e-6f)) * LN2;
    zr[32 + k * 4 + 3] = __builtin_amdgcn_logf(fmaxf(fabsf(l33), 1e-6f)) * LN2;
    zr[64 + k] = pik;
}

// ---------------------------------------------------------------------------
// Kernel B: hot loop only. grid = M*4 blocks x 256 threads; block b: m=b>>2,
// points [(b&3)*1024,+1024), wave w owns 256 (4/lane). Params read at a
// blockIdx-uniform address (-> scalar s_load broadcast; no LDS, no setup
// chain, no barriers). Wave butterfly-reduce; lanes 0-7 store partials
// transposed for coalesced reading in gmm_norm.
// NOTE: per-point softmax MUST keep max-subtraction (R3 bug: collective exp2
// underflow zeroes responsibility mass).
// NOTE: no 2nd __launch_bounds__ arg (R4: treated as min-blocks/CU -> VGPR=64
// -> 458 MB/dispatch scratch spill).
// ---------------------------------------------------------------------------
__global__ __launch_bounds__(256) void gmm_main(const float* __restrict__ ws,
                                                const float* __restrict__ X,
                                                float* __restrict__ part,
                                                int M) {
    const int b = blockIdx.x;
    const int m = b >> 2;
    const int sub = b & 3;
    const int t = threadIdx.x;
    const int w = t >> 6;
    const int lane = t & 63;

    const float4* X4 = reinterpret_cast<const float4*>(X);
    float4 xv[4];
    #pragma unroll
    for (int i = 0; i < 4; ++i)
        xv[i] = X4[sub * 1024 + w * 256 + i * 64 + lane];

    const float4* Pm = reinterpret_cast<const float4*>(ws) + m * 32;  // uniform

    float acc[KK];
    #pragma unroll
    for (int k = 0; k < KK; ++k) acc[k] = 0.f;

    float lj[4][KK];
    #pragma unroll
    for (int k = 0; k < KK; ++k) {
        float4 p0 = Pm[k * 4 + 0], p1 = Pm[k * 4 + 1],
               p2 = Pm[k * 4 + 2], p3 = Pm[k * 4 + 3];
        // mu=p0; w00,w10,w11,w20=p1; w21,w22,w30,w31=p2; w32,w33,c2=p3
        #pragma unroll
        for (int i = 0; i < 4; ++i) {
            float d0 = xv[i].x - p0.x;
            float d1 = xv[i].y - p0.y;
            float d2 = xv[i].z - p0.z;
            float d3 = xv[i].w - p0.w;
            float a0 = d0 * p1.x;
            float a1 = fmaf(p1.y, d0, d1 * p1.z);
            float a2 = fmaf(p1.w, d0, fmaf(p2.x, d1, d2 * p2.y));
            float a3 = fmaf(p2.z, d0, fmaf(p2.w, d1, fmaf(p3.x, d2, d3 * p3.y)));
            float sq = fmaf(a0, a0, fmaf(a1, a1, fmaf(a2, a2, a3 * a3)));
            lj[i][k] = fmaf(-HL2E, sq, p3.z);          // log2-domain
        }
    }
    #pragma unroll
    for (int i = 0; i < 4; ++i) {
        float mx = lj[i][0];
        #pragma unroll
        for (int k = 1; k < KK; ++k) mx = fmaxf(mx, lj[i][k]);
        float e[KK], s = 0.f;
        #pragma unroll
        for (int k = 0; k < KK; ++k) {
            e[k] = __builtin_amdgcn_exp2f(lj[i][k] - mx);  // bare v_exp_f32
            s += e[k];
        }
        float inv = __builtin_amdgcn_rcpf(s);          // s >= 1 (max term = 1)
        #pragma unroll
        for (int k = 0; k < KK; ++k) acc[k] = fmaf(e[k], inv, acc[k]);
    }

    // per-wave butterfly reduce; lanes 0-7 store this wave's partials
    #pragma unroll
    for (int k = 0; k < KK; ++k) {
        float v = acc[k];
        #pragma unroll
        for (int off = 32; off; off >>= 1) v += __shfl_xor(v, off, 64);
        acc[k] = v;
    }
    if (lane < KK) {
        int p = sub * 4 + w;                           // 16 partials per m
        part[(p * KK + lane) * M + m] = acc[lane];
    }
}

// ---------------------------------------------------------------------------
// Kernel C: column z-normalization (ddof=1), in place on d_out. 80 blocks x
// 512 threads (one row each). cols 0-71 already in z (written by gmm_setup);
// cols 72-79 = sum of 16 coalesced partials (B-scaled; z-norm is
// scale-invariant — R5-verified). Branch is block-uniform.
// ---------------------------------------------------------------------------
__global__ __launch_bounds__(512) void gmm_norm(const float* __restrict__ part,
                                                float* __restrict__ z, int M) {
    __shared__ float sw[8];
    const int col = blockIdx.x;
    const int t = threadIdx.x;    // row m

    float v;
    if (col < 72) {
        v = z[t * 80 + col];
    } else {
        int k = col - 72;
        v = 0.f;
        #pragma unroll
        for (int q = 0; q < 16; ++q) v += part[(q * KK + k) * M + t];
    }

    float r = v;
    #pragma unroll
    for (int off = 32; off; off >>= 1) r += __shfl_xor(r, off, 64);
    if ((t & 63) == 0) sw[t >> 6] = r;
    __syncthreads();
    float tot = 0.f;
    #pragma unroll
    for (int w = 0; w < 8; ++w) tot += sw[w];
    float mean = tot / (float)M;
    __syncthreads();

    float d = v - mean;
    r = d * d;
    #pragma unroll
    for (int off = 32; off; off >>= 1) r += __shfl_xor(r, off, 64);
    if ((t & 63) == 0) sw[t >> 6] = r;
    __syncthreads();
    float tot2 = 0.f;
    #pragma unroll
    for (int w = 0; w < 8; ++w) tot2 += sw[w];
    float stdv = fmaxf(sqrtf(tot2 / (float)(M - 1)), 1e-6f);

    z[t * 80 + col] = d / stdv;
}

extern "C" void kernel_launch(void* const* d_in, const int* in_sizes, int n_in,
                              void* d_out, int out_size, void* d_ws, size_t ws_size,
                              hipStream_t stream) {
    const float* phi = (const float*)d_in[0];
    const float* X   = (const float*)d_in[1];
    const int M = in_sizes[0] / 120;  // 512
    float* ws   = (float*)d_ws;       // params: 64K floats
    float* part = ws + 65536;         // partials: 64K floats
    float* z    = (float*)d_out;

    gmm_setup<<<(M * KK) / 256, 256, 0, stream>>>(phi, ws, z);
    gmm_main<<<M * 4, 256, 0, stream>>>(ws, X, part, M);
    gmm_norm<<<80, 512, 0, stream>>>(part, z, M);
}